// Round 8
// baseline (9512.215 us; speedup 1.0000x reference)
//
#include <hip/hip_runtime.h>

typedef _Float16 f16;
typedef _Float16 f16x8 __attribute__((ext_vector_type(8)));
typedef float    f32x4 __attribute__((ext_vector_type(4)));
typedef unsigned int uint;

#define ALPHA 0.2f
#define NSTD  0.05f
#define BB 128
#define TT 1024
#define II 64
#define HH 512
#define OO 10

#define MB   16            // all 16 M-rows real (no waste)
#define NBLK (BB / MB)     // 8 blocks, 1 per XCD
#define NW   8             // waves per block
#define NT   4             // N-tiles per wave; 8 waves cover N=512
#define NTR  18            // r tiles: 16 wrec-K + 2 wi-K
#define NSTR 17            // K-tiles 1..17 streamed from packed ws (L2)

#define WS_FRAGS (NW * NSTR * NT * 64)   // 34816 f16x8 frags
#define WS_NEED  (WS_FRAGS * 16)         // 544 KB

// BUILTIN MFMAs ONLY. Session rule: inline-asm v_mfma corrupts (r2, r7) —
// regalloc-inserted copies land in hazard windows the compiler only guards
// for instructions it can see. Weights that don't fit registers are
// STREAMED from L2 (a 1-block/XCD grid makes this ~0.5 TB/s: trivial).
__device__ __forceinline__ f32x4 mfma16(f16x8 a, f16x8 b, f32x4 c) {
    return __builtin_amdgcn_mfma_f32_16x16x32_f16(a, b, c, 0, 0, 0);
}
__device__ __forceinline__ f16x8 pack8(float4 a0, float4 a1) {
    f16x8 v;
    v[0]=(f16)a0.x; v[1]=(f16)a0.y; v[2]=(f16)a0.z; v[3]=(f16)a0.w;
    v[4]=(f16)a1.x; v[5]=(f16)a1.y; v[6]=(f16)a1.z; v[7]=(f16)a1.w;
    return v;
}
// B-frag for tile kt (1..17), column col, k-group lg — from raw params.
__device__ __forceinline__ f16x8 fb_frag(const float* __restrict__ wrec,
                                         const float* __restrict__ wi,
                                         const float* __restrict__ si,
                                         int kt, int col, int lg) {
    f16x8 v;
    if (kt < 16) {
        const float* wp = wrec + (size_t)col*HH + kt*32 + lg*8;
        v = pack8(*(const float4*)wp, *(const float4*)(wp + 4));
    } else {
        const int e0 = (kt - 16)*32 + lg*8;       // wi row 0..63
#pragma unroll
        for (int jj = 0; jj < 8; ++jj)
            v[jj] = (f16)(wi[(size_t)(e0 + jj)*HH + col] * si[e0 + jj]);
    }
    return v;
}

// ---- one-time pack: ws[((g*17 + s)*4 + nt)*64 + l] = B-frag(tile s+1,
//      col 64g+16nt+lr, k-group lg). Wave-contiguous 1 KB segments. ----
__global__ __launch_bounds__(512) void pack_kernel(
    const float* __restrict__ wrec, const float* __restrict__ wi,
    const float* __restrict__ si, uint4* __restrict__ ws)
{
    const int fid = blockIdx.x * 512 + threadIdx.x;   // < WS_FRAGS (=68*512)
    const int l = fid & 63;
    int rest = fid >> 6;
    const int nt = rest & 3; rest >>= 2;
    const int s = rest % NSTR, g = rest / NSTR;
    const int lr = l & 15, lg = l >> 4;
    const int col = 64*g + 16*nt + lr;
    ws[fid] = __builtin_bit_cast(uint4, fb_frag(wrec, wi, si, s + 1, col, lg));
}

// rpack layout (rounds 3/5/6-verified, 0 bank conflicts): f16x8 frag index =
// kt*64 + lg*16 + (lr ^ s(kt,lg)), s = 4*(kt&1)+lg; element jj = k&7.
// Single writer per slot; 1-barrier double-buffered sync (round-6 verbatim).
template<bool PACKED>
__global__ __launch_bounds__(512, 2) void rnn_kernel(
    const float* __restrict__ input, const float* __restrict__ noise,
    const float* __restrict__ wi, const float* __restrict__ si,
    const float* __restrict__ wrec, const float* __restrict__ wo,
    const float* __restrict__ so, const float* __restrict__ h0,
    const uint4* __restrict__ ws, float* __restrict__ out)
{
    __shared__ __align__(16) f16 rpack[2][NTR * 512];  // 36.9 KB (double buffer)
    __shared__ f32x4 opart[2][NW][64];                 // 16 KB (out partials, dbuf)

    const int tid = threadIdx.x, l = tid & 63, g = tid >> 6;   // g = 0..7
    const int lr = l & 15, lg = l >> 4;
    const int b0 = blockIdx.x * MB;

    // ---- register B-frags: wrec K-tile 0 only (16 regs) ----
    f16x8 bw0[NT];
#pragma unroll
    for (int nt = 0; nt < NT; ++nt) {
        const int col = 64*g + 16*nt + lr;
        const float* wp = wrec + (size_t)col*HH + lg*8;
        bw0[nt] = pack8(*(const float4*)wp, *(const float4*)(wp + 4));
    }
    // ---- out weights: wave g covers K-tiles 2g, 2g+1 ----
    f16x8 bwo[2];
    {
        const float s = (lr < OO) ? so[lr] * (1.0f/ALPHA) : 0.0f;
#pragma unroll
        for (int k2 = 0; k2 < 2; ++k2) {
            f16x8 v;
#pragma unroll
            for (int jj = 0; jj < 8; ++jj) {
                const int k = (2*g + k2)*32 + lg*8 + jj;   // < 512
                v[jj] = (f16)((lr < OO) ? wo[(size_t)k*OO + lr] * s : 0.0f);
            }
            bwo[k2] = v;
        }
    }

    // ---- swizzled A-read offsets ----
    const int ide = lg*16 + (lr ^ lg);        // even tiles
    const int ido = lg*16 + (lr ^ (4 + lg));  // odd tiles

    // ---- publish bases for h (row = 4lg+rr, col = 64g+16nt+lr) ----
    int wbase[NT], wxor[NT];
#pragma unroll
    for (int nt = 0; nt < NT; ++nt) {
        const int col = 64*g + 16*nt + lr;
        const int ktw = col >> 5, lgw = (col >> 3) & 3, j = col & 7;
        const int s = 4*(ktw & 1) + lgw;
        wbase[nt] = ktw*512 + lgw*128 + ((4*lg) ^ (s & 4))*8 + j;
        wxor[nt]  = (s & 3)*8;
    }
    // x publish: thread owns rows (xrow, xrow+8) at col xii — both REAL at MB=16
    const int xrow = tid >> 6, xii = tid & 63;
    const int xkt = 16 + (xii >> 5), xlg = (xii >> 3) & 3;
    const int xsw = 4*(xkt & 1) + xlg;
    const int xbi  = xkt*512 + xlg*128 + ((xrow    ) ^ xsw)*8 + (xii & 7);
    const int xbi2 = xkt*512 + xlg*128 + ((xrow + 8) ^ xsw)*8 + (xii & 7);

    // ---- state: hs[nt][rr] = h[row 4lg+rr][col 64g+16nt+lr] (C/D layout) ----
    f32x4 hs[NT];
#pragma unroll
    for (int nt = 0; nt < NT; ++nt) {
        const float v = h0[64*g + 16*nt + lr];
        hs[nt] = f32x4{v, v, v, v};
    }

    // ---- noise: every lane owns rows 4lg+rr; depth-1 register prefetch ----
    const float* np[4];
#pragma unroll
    for (int rr = 0; rr < 4; ++rr)
        np[rr] = noise + (size_t)(b0 + 4*lg + rr)*TT*HH + 64*g + lr;
    float nz[NT][4];
#pragma unroll
    for (int nt = 0; nt < NT; ++nt)
#pragma unroll
        for (int rr = 0; rr < 4; ++rr) nz[nt][rr] = np[rr][16*nt];   // n_0

    // ---- x staging (two rows per thread), one step ahead ----
    const float* xp  = input + (size_t)(b0 + xrow)*TT*II + xii;
    const float* xp2 = input + (size_t)(b0 + xrow + 8)*TT*II + xii;
    float xv = xp[0], xv2 = xp2[0];                    // x_0

    // ---- stream base: wave g's slice, frag (s, nt) at wsg[s*256 + nt*64] ----
    const uint4* wsg = ws + (size_t)g * (NSTR * NT * 64) + l;

    // ---- publish r_0 + alpha*x_0 into buffer 0 (single writer per slot) ----
#pragma unroll
    for (int nt = 0; nt < NT; ++nt)
#pragma unroll
        for (int rr = 0; rr < 4; ++rr)
            rpack[0][wbase[nt] + ((rr*8) ^ wxor[nt])] =
                (f16)(ALPHA * fmaxf(hs[nt][rr], 0.0f));
    rpack[0][xbi]  = (f16)(ALPHA * xv);
    rpack[0][xbi2] = (f16)(ALPHA * xv2);
    xv = xp[II]; xv2 = xp2[II];                        // x_1

    float* outb = out + (size_t)b0 * TT * OO;

    __syncthreads();

#define WISSUE(dst, sidx) do { \
    if (PACKED) { \
        _Pragma("unroll") for (int nt_ = 0; nt_ < NT; ++nt_) \
            dst[nt_] = __builtin_bit_cast(f16x8, wsg[(sidx)*(NT*64) + nt_*64]); \
    } else { \
        _Pragma("unroll") for (int nt_ = 0; nt_ < NT; ++nt_) \
            dst[nt_] = fb_frag(wrec, wi, si, (sidx) + 1, 64*g + 16*nt_ + lr, lg); \
    } } while (0)

    int cur = 0;
#pragma unroll 1
    for (int t = 0; t < TT; ++t) {
        const f16x8* rvb = (const f16x8*)rpack[cur];

        // stream window: issue tiles 1,2 immediately (cover = preacc+out+reg0)
        f16x8 sw0[NT], sw1[NT];
        WISSUE(sw0, 0);
        WISSUE(sw1, 1);

        // C pre-accumulate: (1-a)h + sigma*n_t ; then prefetch n_{t+1}
#pragma unroll
        for (int nt = 0; nt < NT; ++nt)
#pragma unroll
            for (int rr = 0; rr < 4; ++rr)
                hs[nt][rr] = (1.0f - ALPHA)*hs[nt][rr] + NSTD*nz[nt][rr];
        if (t + 1 < TT) {
#pragma unroll
            for (int nt = 0; nt < NT; ++nt)
#pragma unroll
                for (int rr = 0; rr < 4; ++rr)
                    nz[nt][rr] = np[rr][(size_t)(t + 1)*HH + 16*nt];
        }

        // out-MFMA: wave g's K-tiles 2g,2g+1 of out[t] = relu(h_t) @ wo'
        {
            const f16x8 aA = rvb[(2*g)*64 + ide];
            const f16x8 aB = rvb[(2*g + 1)*64 + ido];
            f32x4 oacc = mfma16(aA, bwo[0], f32x4{0.f, 0.f, 0.f, 0.f});
            oacc = mfma16(aB, bwo[1], oacc);
            opart[cur][g][l] = oacc;
        }

        // reg tile 0
        {
            const f16x8 a = rvb[0*64 + ide];
#pragma unroll
            for (int nt = 0; nt < NT; ++nt) hs[nt] = mfma16(a, bw0[nt], hs[nt]);
        }
        // streamed tiles 1..17, window-2 rotation (consume j, reissue j+2)
#pragma unroll
        for (int j = 0; j < NSTR; ++j) {
            const int kt = j + 1;
            const f16x8 a = rvb[kt*64 + ((kt & 1) ? ido : ide)];
            if (j & 1) {
#pragma unroll
                for (int nt = 0; nt < NT; ++nt) hs[nt] = mfma16(a, sw1[nt], hs[nt]);
                if (j + 2 < NSTR) WISSUE(sw1, j + 2);
            } else {
#pragma unroll
                for (int nt = 0; nt < NT; ++nt) hs[nt] = mfma16(a, sw0[nt], hs[nt]);
                if (j + 2 < NSTR) WISSUE(sw0, j + 2);
            }
        }

        // publish r_{t+1} + alpha*x_{t+1} into the other buffer
        const int nxt = cur ^ 1;
#pragma unroll
        for (int nt = 0; nt < NT; ++nt)
#pragma unroll
            for (int rr = 0; rr < 4; ++rr)
                rpack[nxt][wbase[nt] + ((rr*8) ^ wxor[nt])] =
                    (f16)(ALPHA * fmaxf(hs[nt][rr], 0.0f));
        rpack[nxt][xbi]  = (f16)(ALPHA * xv);
        rpack[nxt][xbi2] = (f16)(ALPHA * xv2);
        if (t + 2 < TT) { xv = xp[(size_t)(t + 2)*II]; xv2 = xp2[(size_t)(t + 2)*II]; }

        __syncthreads();   // rpack[nxt] + opart[cur] visible

        if (g == NW - 1 && t > 0) {
            f32x4 s = opart[cur][0][l];
#pragma unroll
            for (int w = 1; w < NW; ++w) s += opart[cur][w][l];
            if (lr < OO) {
#pragma unroll
                for (int rr = 0; rr < 4; ++rr)
                    outb[((size_t)(4*lg + rr)*TT + (t - 1))*OO + lr] = s[rr];
            }
        }
        cur = nxt;
    }
#undef WISSUE

    // drain: out[T-1] from rpack[cur] = alpha*relu(h_T)
    {
        const f16x8* rvb = (const f16x8*)rpack[cur];
        const f16x8 aA = rvb[(2*g)*64 + ide];
        const f16x8 aB = rvb[(2*g + 1)*64 + ido];
        f32x4 oacc = mfma16(aA, bwo[0], f32x4{0.f, 0.f, 0.f, 0.f});
        oacc = mfma16(aB, bwo[1], oacc);
        opart[cur][g][l] = oacc;
    }
    __syncthreads();
    if (g == NW - 1) {
        f32x4 s = opart[cur][0][l];
#pragma unroll
        for (int w = 1; w < NW; ++w) s += opart[cur][w][l];
        if (lr < OO) {
#pragma unroll
            for (int rr = 0; rr < 4; ++rr)
                outb[((size_t)(4*lg + rr)*TT + (TT - 1))*OO + lr] = s[rr];
        }
    }
}

extern "C" void kernel_launch(void* const* d_in, const int* in_sizes, int n_in,
                              void* d_out, int out_size, void* d_ws, size_t ws_size,
                              hipStream_t stream) {
    const float* input = (const float*)d_in[0];
    const float* noise = (const float*)d_in[1];
    const float* wi    = (const float*)d_in[2];
    const float* si    = (const float*)d_in[3];
    const float* wrec  = (const float*)d_in[4];
    const float* wo    = (const float*)d_in[5];
    const float* so    = (const float*)d_in[6];
    const float* h0    = (const float*)d_in[7];
    float* out = (float*)d_out;
    (void)in_sizes; (void)n_in; (void)out_size;

    if (ws_size >= (size_t)WS_NEED) {
        uint4* ws = (uint4*)d_ws;
        pack_kernel<<<dim3(WS_FRAGS / 512), dim3(512), 0, stream>>>(wrec, wi, si, ws);
        rnn_kernel<true><<<dim3(NBLK), dim3(512), 0, stream>>>(
            input, noise, wi, si, wrec, wo, so, h0, ws, out);
    } else {
        rnn_kernel<false><<<dim3(NBLK), dim3(512), 0, stream>>>(
            input, noise, wi, si, wrec, wo, so, h0, nullptr, out);
    }
}